// Round 6
// baseline (214.455 us; speedup 1.0000x reference)
//
#include <hip/hip_runtime.h>
#include <hip/hip_bf16.h>

#define HW_  9216        // 96*96
#define CHW_ 2359296     // 256*9216

typedef __attribute__((ext_vector_type(8))) short bf16x8;
typedef __attribute__((ext_vector_type(4))) float f32x4;

__device__ __forceinline__ short f2bf(float f) {
  union { float f; unsigned u; } v; v.f = f;
  unsigned r = v.u + 0x7fff + ((v.u >> 16) & 1);   // RNE, no NaNs in this data
  return (short)(r >> 16);
}
__device__ __forceinline__ float bflo(unsigned u) {
  union { unsigned u; float f; } v; v.u = u << 16; return v.f;
}
__device__ __forceinline__ float bfhi(unsigned u) {
  union { unsigned u; float f; } v; v.u = u & 0xffff0000u; return v.f;
}

// bilinear combine of 4 packed-bf16 corners (8 channels) -> bf16 A-fragment
__device__ __forceinline__ bf16x8 combine4(const uint4 g0, const uint4 g1,
                                           const uint4 g2, const uint4 g3,
                                           const float4 w) {
  bf16x8 r;
#define CMB(gw0, gw1, gw2, gw3, e)                                              \
  r[e]     = f2bf(w.x * bflo(gw0) + w.y * bflo(gw1) + w.z * bflo(gw2) + w.w * bflo(gw3)); \
  r[(e)+1] = f2bf(w.x * bfhi(gw0) + w.y * bfhi(gw1) + w.z * bfhi(gw2) + w.w * bfhi(gw3));
  CMB(g0.x, g1.x, g2.x, g3.x, 0)
  CMB(g0.y, g1.y, g2.y, g3.y, 2)
  CMB(g0.z, g1.z, g2.z, g3.z, 4)
  CMB(g0.w, g1.w, g2.w, g3.w, 6)
#undef CMB
  return r;
}

// ---------------- x: NCHW f32 -> NHWC bf16 ----------------
__global__ void k_transpose2(const float* __restrict__ x, short* __restrict__ xt) {
  __shared__ float tile[32][33];
  const int b = blockIdx.z;
  const int hw0 = blockIdx.x * 32;
  const int c0 = blockIdx.y * 32;
  const int tx = threadIdx.x, ty = threadIdx.y;   // 32 x 8
  const float* xb = x + (size_t)b * CHW_;
  short* xtb = xt + (size_t)b * CHW_;
#pragma unroll
  for (int s = 0; s < 4; ++s)
    tile[ty + s * 8][tx] = xb[(size_t)(c0 + ty + s * 8) * HW_ + hw0 + tx];
  __syncthreads();
  const int tid = ty * 32 + tx;
  const int cp = tid & 15;    // channel pair
  const int hh = tid >> 4;    // 0..15
#pragma unroll
  for (int s = 0; s < 2; ++s) {
    const int hw = hh + s * 16;
    short2 v;
    v.x = f2bf(tile[2 * cp][hw]);
    v.y = f2bf(tile[2 * cp + 1][hw]);
    *(short2*)&xtb[(size_t)(hw0 + hw) * 256 + c0 + 2 * cp] = v;
  }
}

// ------- prep: deform_w + offset_w -> bf16 MFMA b-fragment layouts -------
__global__ void k_prep(const float* __restrict__ dw, const float* __restrict__ ow,
                       short* __restrict__ wfrag, short* __restrict__ owfrag) {
  const int idx = blockIdx.x * 256 + threadIdx.x;
  if (idx < 589824) {
    const int i = idx & 7, l = (idx >> 3) & 63, nf = (idx >> 9) & 15, kb = idx >> 13;
    const int o = nf * 16 + (l & 15);
    const int c = (kb & 7) * 32 + (l >> 4) * 8 + i;
    const int kk = kb >> 3;
    wfrag[idx] = f2bf(dw[(size_t)(o * 256 + c) * 9 + kk]);
  } else {
    const int j = idx - 589824;   // < 73728
    const int i = j & 7, l = (j >> 3) & 63, nf = (j >> 9) & 1, s = j >> 10;
    const int o = nf * 16 + (l & 15);
    const int c = ((s & 7) << 5) + ((l >> 4) << 3) + i;
    const int kk = s >> 3;
    owfrag[j] = (o < 18) ? f2bf(ow[(size_t)(o * 256 + c) * 9 + kk]) : (short)0;
  }
}

// ---- fused: offset conv (phase A, MFMA) + metadata (B) + deform GEMM (C) ----
// 1152 blocks x 128 threads. Block = 1 ho row x 32 wo pixels, all 256 outputs.
// Phase C: waves split M (wave w owns pixels w*16..w*16+15, all 256 outputs).
// A-fragments gathered per-lane into registers (no LDS); B-tile LDS-shared,
// double-buffered, reg-staged (T14: load at top, ds_write after MFMAs).
__global__ __launch_bounds__(128) void k_deform(
    const short* __restrict__ xt, const short* __restrict__ wfrag,
    const short* __restrict__ owfrag, const float* __restrict__ ob,
    const float* __restrict__ db, float* __restrict__ out) {
  __shared__ __align__(16) char smem[39680];
  char*   bbuf = smem;                       // 2 x 16KB B double-buffer
  float*  offsLDS = (float*)smem;            // [32][32] f32 overlay (phase A out)
  float4* mwP = (float4*)(smem + 32768);     // [288] bilinear weights
  short4* miP = (short4*)(smem + 37376);     // [288] corner pixel indices

  const int tid = threadIdx.x;
  // XCD-aware bijective swizzle: 1152 = 8 XCDs x 144 contiguous strips
  const int blk0 = blockIdx.x;
  const int blk = (blk0 & 7) * 144 + (blk0 >> 3);
  const int b = blk / 288;
  const int r = blk % 288;
  const int ho0 = r / 3;
  const int wo0 = (r % 3) * 32;
  const short* xb = xt + (size_t)b * CHW_;
  const int lane = tid & 63;
  const int wave = tid >> 6;   // 0..1

  // ---- phase A: offset conv for this block's 32 pixels (register MFMA) ----
  {
    const int pA = wave * 16 + (lane & 15);      // pixel 0..31
    const int woA = wo0 + pA;
    const int coff = (lane >> 4) << 3;
    f32x4 oa0 = {0.f, 0.f, 0.f, 0.f}, oa1 = {0.f, 0.f, 0.f, 0.f};
#pragma unroll 4
    for (int s = 0; s < 72; ++s) {
      const int kk = s >> 3;
      const int c0 = (s & 7) << 5;
      const int y = ho0 - 1 + kk / 3;
      const int x = woA - 1 + kk % 3;
      bf16x8 af = {0, 0, 0, 0, 0, 0, 0, 0};
      if ((unsigned)y < 96u && (unsigned)x < 96u)
        af = *(const bf16x8*)(xb + ((y * 96 + x) << 8) + c0 + coff);
      const bf16x8 b0 = *(const bf16x8*)(owfrag + (size_t)s * 1024 + lane * 8);
      const bf16x8 b1 = *(const bf16x8*)(owfrag + (size_t)s * 1024 + 512 + lane * 8);
      oa0 = __builtin_amdgcn_mfma_f32_16x16x32_bf16(af, b0, oa0, 0, 0, 0);
      oa1 = __builtin_amdgcn_mfma_f32_16x16x32_bf16(af, b1, oa1, 0, 0, 0);
    }
    const int r0 = wave * 16 + (lane >> 4) * 4;
    const int cc = lane & 15;
#pragma unroll
    for (int j = 0; j < 4; ++j) {
      offsLDS[(r0 + j) * 32 + cc] = oa0[j];
      offsLDS[(r0 + j) * 32 + 16 + cc] = oa1[j];
    }
  }
  __syncthreads();

  // ---- phase B: sampling metadata: 9 kk x 32 pixels ----
  for (int u = tid; u < 288; u += 128) {
    const int kk = u >> 5;
    const int p = u & 31;
    const int wo = wo0 + p;
    const float dy = offsLDS[p * 32 + 2 * kk] + ob[2 * kk];
    const float dx = offsLDS[p * 32 + 2 * kk + 1] + ob[2 * kk + 1];
    const float py = (float)(ho0 - 1 + kk / 3) + dy;
    const float px = (float)(wo - 1 + kk % 3) + dx;
    const float y0f = floorf(py), x0f = floorf(px);
    const float ty = py - y0f, tx = px - x0f;
    const int y0 = (int)y0f, x0 = (int)x0f;
    const int y1 = y0 + 1, x1 = x0 + 1;
    const float vy0 = ((unsigned)y0 < 96u) ? 1.f : 0.f;
    const float vy1 = ((unsigned)y1 < 96u) ? 1.f : 0.f;
    const float vx0 = ((unsigned)x0 < 96u) ? 1.f : 0.f;
    const float vx1 = ((unsigned)x1 < 96u) ? 1.f : 0.f;
    const float oy = 1.f - ty, ox = 1.f - tx;
    float4 w4;
    w4.x = oy * ox * vy0 * vx0;
    w4.y = oy * tx * vy0 * vx1;
    w4.z = ty * ox * vy1 * vx0;
    w4.w = ty * tx * vy1 * vx1;
    const int cy0 = min(max(y0, 0), 95), cy1 = min(max(y1, 0), 95);
    const int cx0 = min(max(x0, 0), 95), cx1 = min(max(x1, 0), 95);
    mwP[u] = w4;
    miP[u] = make_short4((short)(cy0 * 96 + cx0), (short)(cy0 * 96 + cx1),
                         (short)(cy1 * 96 + cx0), (short)(cy1 * 96 + cx1));
  }
  __syncthreads();

  // ---- phase C ----
  const int p = wave * 16 + (lane & 15);   // this lane's pixel (A row)
  const int kc8 = (lane >> 4) << 3;        // k-chunk within 32

  f32x4 acc[16];
#pragma unroll
  for (int j = 0; j < 16; ++j) acc[j] = (f32x4){0.f, 0.f, 0.f, 0.f};

  // prologue: metadata kk=0, corners kb=0, stage B kb=0 -> buf0
  float4 w4c = mwP[p];
  short4 m0 = miP[p];
  int4 a4c;
  a4c.x = ((int)m0.x) << 8; a4c.y = ((int)m0.y) << 8;
  a4c.z = ((int)m0.z) << 8; a4c.w = ((int)m0.w) << 8;
  uint4 Gc0 = *(const uint4*)(xb + a4c.x + kc8);
  uint4 Gc1 = *(const uint4*)(xb + a4c.y + kc8);
  uint4 Gc2 = *(const uint4*)(xb + a4c.z + kc8);
  uint4 Gc3 = *(const uint4*)(xb + a4c.w + kc8);
  {
    const short* gs = wfrag + (((size_t)wave * 8) * 64 + lane) * 8;
    uint4 Bs[8];
#pragma unroll
    for (int jj = 0; jj < 8; ++jj) Bs[jj] = *(const uint4*)(gs + jj * 512);
    short* ls = (short*)bbuf + wave * 4096 + lane * 8;
#pragma unroll
    for (int jj = 0; jj < 8; ++jj) *(uint4*)(ls + jj * 512) = Bs[jj];
  }
  __syncthreads();

  for (int kb = 0; kb < 72; ++kb) {
    const short* bs = (const short*)(bbuf + (kb & 1) * 16384);
    const int kbn = kb + 1;
    float4 w4n = w4c;
    int4 a4n = a4c;
    uint4 Gn0 = Gc0, Gn1 = Gc1, Gn2 = Gc2, Gn3 = Gc3;
    uint4 Bs[8];
    if (kb < 71) {
      if ((kbn & 7) == 0) {
        const int kkn = kbn >> 3;
        w4n = mwP[kkn * 32 + p];
        const short4 mn = miP[kkn * 32 + p];
        a4n.x = ((int)mn.x) << 8; a4n.y = ((int)mn.y) << 8;
        a4n.z = ((int)mn.z) << 8; a4n.w = ((int)mn.w) << 8;
      }
      const int cb = ((kbn & 7) << 5) + kc8;
      Gn0 = *(const uint4*)(xb + a4n.x + cb);
      Gn1 = *(const uint4*)(xb + a4n.y + cb);
      Gn2 = *(const uint4*)(xb + a4n.z + cb);
      Gn3 = *(const uint4*)(xb + a4n.w + cb);
      const short* gs = wfrag + (((size_t)kbn * 16 + wave * 8) * 64 + lane) * 8;
#pragma unroll
      for (int jj = 0; jj < 8; ++jj) Bs[jj] = *(const uint4*)(gs + jj * 512);
    }
    // combine current corners -> A-fragment (registers only)
    const bf16x8 af = combine4(Gc0, Gc1, Gc2, Gc3, w4c);
    // 16 MFMAs: all 256 outputs for this wave's 16 pixels
#pragma unroll
    for (int j = 0; j < 16; ++j) {
      const bf16x8 bfr = *(const bf16x8*)(bs + j * 512 + lane * 8);
      acc[j] = __builtin_amdgcn_mfma_f32_16x16x32_bf16(af, bfr, acc[j], 0, 0, 0);
    }
    // write staged B-tile for kb+1 into the other buffer
    if (kb < 71) {
      short* ls = (short*)(bbuf + (kbn & 1) * 16384) + wave * 4096 + lane * 8;
#pragma unroll
      for (int jj = 0; jj < 8; ++jj) *(uint4*)(ls + jj * 512) = Bs[jj];
    }
    __syncthreads();
    Gc0 = Gn0; Gc1 = Gn1; Gc2 = Gn2; Gc3 = Gn3;
    w4c = w4n; a4c = a4n;
  }

  // ---- epilogue: acc[j] regs = 4 consecutive pixels -> float4 stores ----
  const int col = lane & 15;
  const int rg = lane >> 4;
  const int pixbase = ho0 * 96 + wo0 + wave * 16 + rg * 4;
#pragma unroll
  for (int j = 0; j < 16; ++j) {
    const int o = j * 16 + col;
    const float bv = db[o];
    float4 v;
    v.x = acc[j][0] + bv;
    v.y = acc[j][1] + bv;
    v.z = acc[j][2] + bv;
    v.w = acc[j][3] + bv;
    *(float4*)(out + (size_t)(b * 256 + o) * HW_ + pixbase) = v;
  }
}

extern "C" void kernel_launch(void* const* d_in, const int* in_sizes, int n_in,
                              void* d_out, int out_size, void* d_ws, size_t ws_size,
                              hipStream_t stream) {
  const float* x  = (const float*)d_in[0];
  const float* ow = (const float*)d_in[1];
  const float* ob = (const float*)d_in[2];
  const float* dw = (const float*)d_in[3];
  const float* db = (const float*)d_in[4];
  float* out = (float*)d_out;
  float* ws = (float*)d_ws;

  short* xt     = (short*)ws;                // 9,437,184 bf16 (18.9 MB)
  short* wfrag  = (short*)(ws + 4718592);    //   589,824 bf16
  short* owfrag = wfrag + 589824;            //    73,728 bf16  (~20.2 MB total)

  hipLaunchKernelGGL(k_transpose2, dim3(288, 8, 4), dim3(32, 8, 1), 0, stream, x, xt);
  hipLaunchKernelGGL(k_prep, dim3(2592), dim3(256), 0, stream, dw, ow, wfrag, owfrag);
  hipLaunchKernelGGL(k_deform, dim3(1152), dim3(128), 0, stream,
                     xt, wfrag, owfrag, ob, db, out);
}

// Round 7
// 168.667 us; speedup vs baseline: 1.2715x; 1.2715x over previous
//
#include <hip/hip_runtime.h>
#include <hip/hip_bf16.h>

#define HW_  9216        // 96*96
#define CHW_ 2359296     // 256*9216

typedef __attribute__((ext_vector_type(8))) short bf16x8;
typedef __attribute__((ext_vector_type(4))) float f32x4;

__device__ __forceinline__ short f2bf(float f) {
  union { float f; unsigned u; } v; v.f = f;
  unsigned r = v.u + 0x7fff + ((v.u >> 16) & 1);   // RNE, no NaNs in this data
  return (short)(r >> 16);
}
__device__ __forceinline__ float bflo(unsigned u) {
  union { unsigned u; float f; } v; v.u = u << 16; return v.f;
}
__device__ __forceinline__ float bfhi(unsigned u) {
  union { unsigned u; float f; } v; v.u = u & 0xffff0000u; return v.f;
}

// ---------------- x: NCHW f32 -> NHWC bf16 ----------------
__global__ void k_transpose2(const float* __restrict__ x, short* __restrict__ xt) {
  __shared__ float tile[32][33];
  const int b = blockIdx.z;
  const int hw0 = blockIdx.x * 32;
  const int c0 = blockIdx.y * 32;
  const int tx = threadIdx.x, ty = threadIdx.y;   // 32 x 8
  const float* xb = x + (size_t)b * CHW_;
  short* xtb = xt + (size_t)b * CHW_;
#pragma unroll
  for (int s = 0; s < 4; ++s)
    tile[ty + s * 8][tx] = xb[(size_t)(c0 + ty + s * 8) * HW_ + hw0 + tx];
  __syncthreads();
  const int tid = ty * 32 + tx;
  const int cp = tid & 15;    // channel pair
  const int hh = tid >> 4;    // 0..15
#pragma unroll
  for (int s = 0; s < 2; ++s) {
    const int hw = hh + s * 16;
    short2 v;
    v.x = f2bf(tile[2 * cp][hw]);
    v.y = f2bf(tile[2 * cp + 1][hw]);
    *(short2*)&xtb[(size_t)(hw0 + hw) * 256 + c0 + 2 * cp] = v;
  }
}

// ------- prep: deform_w + offset_w -> bf16 MFMA b-fragment layouts -------
__global__ void k_prep(const float* __restrict__ dw, const float* __restrict__ ow,
                       short* __restrict__ wfrag, short* __restrict__ owfrag) {
  const int idx = blockIdx.x * 256 + threadIdx.x;
  if (idx < 589824) {
    const int i = idx & 7, l = (idx >> 3) & 63, nf = (idx >> 9) & 15, kb = idx >> 13;
    const int o = nf * 16 + (l & 15);
    const int c = (kb & 7) * 32 + (l >> 4) * 8 + i;
    const int kk = kb >> 3;
    wfrag[idx] = f2bf(dw[(size_t)(o * 256 + c) * 9 + kk]);
  } else {
    const int j = idx - 589824;   // < 73728
    const int i = j & 7, l = (j >> 3) & 63, nf = (j >> 9) & 1, s = j >> 10;
    const int o = nf * 16 + (l & 15);
    const int c = ((s & 7) << 5) + ((l >> 4) << 3) + i;
    const int kk = s >> 3;
    owfrag[j] = (o < 18) ? f2bf(ow[(size_t)(o * 256 + c) * 9 + kk]) : (short)0;
  }
}

// ---- fused: offset conv (phase A, MFMA) + metadata (B) + deform GEMM (C) ----
// 1152 blocks x 256 threads (4 waves). Block = 1 ho row x 32 wo, all 256 outs.
// Phase C: waves split N (wave w: 32 px x outputs [w*64, w*64+64)).
// A staged in LDS cooperatively (1 task/thread), double-buffered;
// B-fragments in registers straight from L2.
__global__ __launch_bounds__(256) void k_deform(
    const short* __restrict__ xt, const short* __restrict__ wfrag,
    const short* __restrict__ owfrag, const float* __restrict__ ob,
    const float* __restrict__ db, float* __restrict__ out) {
  __shared__ __align__(16) char smem[14336];
  short*  vals = (short*)smem;               // 2 x [32][40] bf16 (double buffer)
  float*  offsLDS = (float*)smem;            // [32][32] f32 overlay (phase A out)
  float4* mw = (float4*)(smem + 5120);       // [288]
  int4*   mi = (int4*)(smem + 9728);         // [288]

  const int tid = threadIdx.x;
  // XCD-aware bijective swizzle: 1152 = 8 XCDs x 144 contiguous strips
  const int blk0 = blockIdx.x;
  const int blk = (blk0 & 7) * 144 + (blk0 >> 3);
  const int b = blk / 288;
  const int r = blk % 288;
  const int ho0 = r / 3;
  const int wo0 = (r % 3) * 32;
  const short* xb = xt + (size_t)b * CHW_;
  const int lane = tid & 63;
  const int wave = tid >> 6;   // 0..3

  // ---- phase A: offset conv, 2x2 wave split (pixel-half x output-frag) ----
  {
    const int wmA = wave & 1;       // pixel half
    const int wnA = wave >> 1;      // output frag (0: o0-15, 1: o16-31)
    const int pA = wmA * 16 + (lane & 15);
    const int woA = wo0 + pA;
    const int coff = (lane >> 4) << 3;
    f32x4 oa = {0.f, 0.f, 0.f, 0.f};
#pragma unroll 4
    for (int s = 0; s < 72; ++s) {
      const int kk = s >> 3;
      const int c0 = (s & 7) << 5;
      const int y = ho0 - 1 + kk / 3;
      const int x = woA - 1 + kk % 3;
      bf16x8 af = {0, 0, 0, 0, 0, 0, 0, 0};
      if ((unsigned)y < 96u && (unsigned)x < 96u)
        af = *(const bf16x8*)(xb + ((y * 96 + x) << 8) + c0 + coff);
      const bf16x8 bo = *(const bf16x8*)(owfrag + (size_t)s * 1024 + wnA * 512 + lane * 8);
      oa = __builtin_amdgcn_mfma_f32_16x16x32_bf16(af, bo, oa, 0, 0, 0);
    }
    const int r0 = wmA * 16 + (lane >> 4) * 4;
    const int cc = lane & 15;
#pragma unroll
    for (int j = 0; j < 4; ++j)
      offsLDS[(r0 + j) * 32 + wnA * 16 + cc] = oa[j];
  }
  __syncthreads();

  // ---- phase B: sampling metadata: 9 kk x 32 pixels ----
  for (int u = tid; u < 288; u += 256) {
    const int kk = u >> 5;
    const int p = u & 31;
    const int wo = wo0 + p;
    const float dy = offsLDS[p * 32 + 2 * kk] + ob[2 * kk];
    const float dx = offsLDS[p * 32 + 2 * kk + 1] + ob[2 * kk + 1];
    const float py = (float)(ho0 - 1 + kk / 3) + dy;
    const float px = (float)(wo - 1 + kk % 3) + dx;
    const float y0f = floorf(py), x0f = floorf(px);
    const float ty = py - y0f, tx = px - x0f;
    const int y0 = (int)y0f, x0 = (int)x0f;
    const int y1 = y0 + 1, x1 = x0 + 1;
    const float vy0 = ((unsigned)y0 < 96u) ? 1.f : 0.f;
    const float vy1 = ((unsigned)y1 < 96u) ? 1.f : 0.f;
    const float vx0 = ((unsigned)x0 < 96u) ? 1.f : 0.f;
    const float vx1 = ((unsigned)x1 < 96u) ? 1.f : 0.f;
    const float oy = 1.f - ty, ox = 1.f - tx;
    float4 w4;
    w4.x = oy * ox * vy0 * vx0;
    w4.y = oy * tx * vy0 * vx1;
    w4.z = ty * ox * vy1 * vx0;
    w4.w = ty * tx * vy1 * vx1;
    const int cy0 = min(max(y0, 0), 95), cy1 = min(max(y1, 0), 95);
    const int cx0 = min(max(x0, 0), 95), cx1 = min(max(x1, 0), 95);
    int4 i4;
    i4.x = (cy0 * 96 + cx0) << 8;
    i4.y = (cy0 * 96 + cx1) << 8;
    i4.z = (cy1 * 96 + cx0) << 8;
    i4.w = (cy1 * 96 + cx1) << 8;
    mw[u] = w4; mi[u] = i4;
  }
  __syncthreads();

  // ---- phase C: deform GEMM, double-buffered, 1 barrier / K-step ----
  const int ms = tid >> 3;    // staging pixel row 0..31
  const int q = tid & 7;      // staging c-quad

  f32x4 acc[2][4];
#pragma unroll
  for (int a = 0; a < 2; ++a)
#pragma unroll
    for (int bb = 0; bb < 4; ++bb) acc[a][bb] = (f32x4){0.f, 0.f, 0.f, 0.f};

  // prologue: stage kb=0 into buf0 (1 task/thread)
  {
    const float4 w4 = mw[ms];
    const int4 i4 = mi[ms];
    const int c = q * 4;
    const uint2 u00 = *(const uint2*)(xb + i4.x + c);
    const uint2 u01 = *(const uint2*)(xb + i4.y + c);
    const uint2 u10 = *(const uint2*)(xb + i4.z + c);
    const uint2 u11 = *(const uint2*)(xb + i4.w + c);
    short4 s4;
    s4.x = f2bf(w4.x * bflo(u00.x) + w4.y * bflo(u01.x) + w4.z * bflo(u10.x) + w4.w * bflo(u11.x));
    s4.y = f2bf(w4.x * bfhi(u00.x) + w4.y * bfhi(u01.x) + w4.z * bfhi(u10.x) + w4.w * bfhi(u11.x));
    s4.z = f2bf(w4.x * bflo(u00.y) + w4.y * bflo(u01.y) + w4.z * bflo(u10.y) + w4.w * bflo(u11.y));
    s4.w = f2bf(w4.x * bfhi(u00.y) + w4.y * bfhi(u01.y) + w4.z * bfhi(u10.y) + w4.w * bfhi(u11.y));
    *reinterpret_cast<short4*>(&vals[ms * 40 + q * 4]) = s4;
  }
  __syncthreads();

  for (int kb = 0; kb < 72; ++kb) {
    const int cur = kb & 1;
    const short* vcur = vals + cur * 1280;
    short* vnxt = vals + (cur ^ 1) * 1280;

    // B-fragments for this wave's 4 n-frags (L2-resident, 16B/lane)
    bf16x8 bfr[4];
    const size_t wbase = ((size_t)(kb * 16 + wave * 4) * 64 + lane) * 8;
#pragma unroll
    for (int j = 0; j < 4; ++j)
      bfr[j] = *(const bf16x8*)(wfrag + wbase + (size_t)j * 512);

    // issue gathers for kb+1 early (overlap with MFMAs below)
    const int kbn = (kb < 71) ? kb + 1 : kb;
    const int kkn = kbn >> 3;
    const int c0n = (kbn & 7) << 5;
    const float4 w4n = mw[kkn * 32 + ms];
    const int4 i4n = mi[kkn * 32 + ms];
    const int cn = c0n + q * 4;
    uint2 U0 = *(const uint2*)(xb + i4n.x + cn);
    uint2 U1 = *(const uint2*)(xb + i4n.y + cn);
    uint2 U2 = *(const uint2*)(xb + i4n.z + cn);
    uint2 U3 = *(const uint2*)(xb + i4n.w + cn);

    // MFMAs on current buffer: 2 m-frags x 4 n-frags
#pragma unroll
    for (int mf = 0; mf < 2; ++mf) {
      const int row = mf * 16 + (lane & 15);
      const bf16x8 af = *(const bf16x8*)(&vcur[row * 40 + (lane >> 4) * 8]);
#pragma unroll
      for (int j = 0; j < 4; ++j)
        acc[mf][j] = __builtin_amdgcn_mfma_f32_16x16x32_bf16(af, bfr[j], acc[mf][j], 0, 0, 0);
    }

    // convert + write next buffer
    if (kb < 71) {
      short4 s4;
      s4.x = f2bf(w4n.x * bflo(U0.x) + w4n.y * bflo(U1.x) + w4n.z * bflo(U2.x) + w4n.w * bflo(U3.x));
      s4.y = f2bf(w4n.x * bfhi(U0.x) + w4n.y * bfhi(U1.x) + w4n.z * bfhi(U2.x) + w4n.w * bfhi(U3.x));
      s4.z = f2bf(w4n.x * bflo(U0.y) + w4n.y * bflo(U1.y) + w4n.z * bflo(U2.y) + w4n.w * bflo(U3.y));
      s4.w = f2bf(w4n.x * bfhi(U0.y) + w4n.y * bfhi(U1.y) + w4n.z * bfhi(U2.y) + w4n.w * bfhi(U3.y));
      *reinterpret_cast<short4*>(&vnxt[ms * 40 + q * 4]) = s4;
    }
    __syncthreads();
  }

  // ---- epilogue: D regs = 4 consecutive pixels -> float4 stores ----
  const int col = lane & 15;
  const int rg = lane >> 4;
#pragma unroll
  for (int mf = 0; mf < 2; ++mf) {
    const int pix = mf * 16 + rg * 4;
#pragma unroll
    for (int j = 0; j < 4; ++j) {
      const int o = wave * 64 + j * 16 + col;
      const float bv = db[o];
      float4 v;
      v.x = acc[mf][j][0] + bv;
      v.y = acc[mf][j][1] + bv;
      v.z = acc[mf][j][2] + bv;
      v.w = acc[mf][j][3] + bv;
      *(float4*)(out + (size_t)(b * 256 + o) * HW_ + ho0 * 96 + wo0 + pix) = v;
    }
  }
}

extern "C" void kernel_launch(void* const* d_in, const int* in_sizes, int n_in,
                              void* d_out, int out_size, void* d_ws, size_t ws_size,
                              hipStream_t stream) {
  const float* x  = (const float*)d_in[0];
  const float* ow = (const float*)d_in[1];
  const float* ob = (const float*)d_in[2];
  const float* dw = (const float*)d_in[3];
  const float* db = (const float*)d_in[4];
  float* out = (float*)d_out;
  float* ws = (float*)d_ws;

  short* xt     = (short*)ws;                // 9,437,184 bf16 (18.9 MB)
  short* wfrag  = (short*)(ws + 4718592);    //   589,824 bf16
  short* owfrag = wfrag + 589824;            //    73,728 bf16  (~20.2 MB total)

  hipLaunchKernelGGL(k_transpose2, dim3(288, 8, 4), dim3(32, 8, 1), 0, stream, x, xt);
  hipLaunchKernelGGL(k_prep, dim3(2592), dim3(256), 0, stream, dw, ow, wfrag, owfrag);
  hipLaunchKernelGGL(k_deform, dim3(1152), dim3(256), 0, stream,
                     xt, wfrag, owfrag, ob, db, out);
}